// Round 11
// baseline (292.305 us; speedup 1.0000x reference)
//
#include <hip/hip_runtime.h>
#include <math.h>

// Shapes (fixed by the reference)
constexpr int Bn  = 16;
constexpr int Sn  = 512;
constexpr int S2n = 64;
constexpr int Hn  = 128;
constexpr int Ln  = 3;

#define TID ((int)threadIdx.x)

__device__ inline float wave_reduce_sum(float v) {
#pragma unroll
  for (int off = 32; off > 0; off >>= 1) v += __shfl_xor(v, off, 64);
  return v;
}

__device__ inline float block_reduce_sum(float v, float* red) {
  v = wave_reduce_sum(v);
  int w  = TID >> 6;
  int nw = (int)blockDim.x >> 6;
  if ((TID & 63) == 0) red[w] = v;
  __syncthreads();
  float s = 0.f;
  for (int i = 0; i < nw; ++i) s += red[i];
  __syncthreads();
  return s;
}

__device__ inline float sigm(float x) { return 1.f / (1.f + expf(-x)); }

// Transposes: z=0: WtRT[k][n] = Wt[n][128+k] (K=128); z=1: Wa1T (K=256).
__global__ __launch_bounds__(256) void transpose2(
    const float* __restrict__ Wt, const float* __restrict__ Wa1,
    float* __restrict__ WtRT, float* __restrict__ Wa1T)
{
  const float* src; float* dst; int K, woff;
  if (blockIdx.z == 0) { src = Wt;  dst = WtRT; K = 128; woff = 128; }
  else                 { src = Wa1; dst = Wa1T; K = 256; woff = 0; }
  int k0 = blockIdx.x * 32;
  if (k0 >= K) return;
  int n0 = blockIdx.y * 32;
  __shared__ float t[32][33];
  int tx = TID & 31, ty = TID >> 5;
#pragma unroll
  for (int i = 0; i < 32; i += 8)
    t[ty + i][tx] = src[(size_t)(n0 + ty + i) * 256 + woff + k0 + tx];
  __syncthreads();
#pragma unroll
  for (int i = 0; i < 32; i += 8)
    dst[(size_t)(k0 + ty + i) * 128 + n0 + tx] = t[tx][ty + i];
}

// Combined matrices: GT[k][n] = sum_c Wn[c][k]*W[n][c] (+ W[n][128+k] for u,r)
// cvec[n] = sum_c bn[c]*W[n][c].
__global__ __launch_bounds__(128) void combine_weights(
    const float* __restrict__ Wn, const float* __restrict__ Wu,
    const float* __restrict__ Wr, const float* __restrict__ Wt,
    const float* __restrict__ bn,
    float* __restrict__ GuT, float* __restrict__ GrT, float* __restrict__ GtT,
    float* __restrict__ cu, float* __restrict__ cr, float* __restrict__ ct)
{
  int n = blockIdx.x, mat = blockIdx.y;
  const float* W; float* GT; float* cv;
  if (mat == 0)      { W = Wu; GT = GuT; cv = cu; }
  else if (mat == 1) { W = Wr; GT = GrT; cv = cr; }
  else               { W = Wt; GT = GtT; cv = ct; }
  __shared__ float Ws[128], bns[128];
  __shared__ float red[2];
  int k = TID;
  Ws[k]  = W[(size_t)n * 256 + k];
  bns[k] = bn[k];
  __syncthreads();
  float acc = 0.f;
#pragma unroll 4
  for (int c = 0; c < 128; ++c)
    acc = fmaf(Wn[(size_t)c * 128 + k], Ws[c], acc);
  if (mat < 2) acc += W[(size_t)n * 256 + 128 + k];
  GT[(size_t)k * 128 + n] = acc;
  float pv = bns[k] * Ws[k];
  pv = wave_reduce_sum(pv);
  if ((k & 63) == 0) red[k >> 6] = pv;
  __syncthreads();
  if (k == 0) cv[n] = red[0] + red[1];
}

// deg[row] = sum_j adj[row][j]
__global__ __launch_bounds__(256) void deg_kernel(
    const float* __restrict__ adj, float* __restrict__ deg)
{
  int wid = TID >> 6, lane = TID & 63;
  int row = blockIdx.x * 4 + wid;
  const float* ar = adj + (size_t)row * Sn;
  float4 a = ((const float4*)ar)[lane];
  float4 b = ((const float4*)ar)[64 + lane];
  float s = a.x + a.y + a.z + a.w + b.x + b.y + b.z + b.w;
  s = wave_reduce_sum(s);
  if (lane == 0) deg[row] = s;
}

// g[row][mat*128 + c] = h @ G_mat (+ct for mat==2). One matrix per blockIdx.y
// -> grid 1536 (3x occupancy). Thread = 2 rows x 4 cols, float4 W loads.
__global__ __launch_bounds__(256) void gemm_g2(
    const float* __restrict__ h, const float* __restrict__ GuT,
    const float* __restrict__ GrT, const float* __restrict__ GtT,
    const float* __restrict__ ctv, float* __restrict__ g)
{
  __shared__ float Xs[16 * 128];
  int r0 = blockIdx.x * 16;
  int mat = blockIdx.y;
  const float* GT = (mat == 0) ? GuT : (mat == 1) ? GrT : GtT;
  const float* xsrc = h + (size_t)r0 * 128;
  for (int i = TID; i < 512; i += 256)
    ((float4*)Xs)[i] = ((const float4*)xsrc)[i];
  __syncthreads();

  int c4 = (TID & 31) * 4;
  int rb = (TID >> 5) * 2;
  float acc[2][4] = {};

#pragma unroll 4
  for (int k = 0; k < 128; k += 4) {
    const float* wk = GT + (size_t)k * 128 + c4;
    float4 w0 = *(const float4*)(wk);
    float4 w1 = *(const float4*)(wk + 128);
    float4 w2 = *(const float4*)(wk + 256);
    float4 w3 = *(const float4*)(wk + 384);
#pragma unroll
    for (int r = 0; r < 2; ++r) {
      float4 x = *(const float4*)&Xs[(rb + r) * 128 + k];
      acc[r][0] = fmaf(x.x, w0.x, acc[r][0]);
      acc[r][0] = fmaf(x.y, w1.x, acc[r][0]);
      acc[r][0] = fmaf(x.z, w2.x, acc[r][0]);
      acc[r][0] = fmaf(x.w, w3.x, acc[r][0]);
      acc[r][1] = fmaf(x.x, w0.y, acc[r][1]);
      acc[r][1] = fmaf(x.y, w1.y, acc[r][1]);
      acc[r][1] = fmaf(x.z, w2.y, acc[r][1]);
      acc[r][1] = fmaf(x.w, w3.y, acc[r][1]);
      acc[r][2] = fmaf(x.x, w0.z, acc[r][2]);
      acc[r][2] = fmaf(x.y, w1.z, acc[r][2]);
      acc[r][2] = fmaf(x.z, w2.z, acc[r][2]);
      acc[r][2] = fmaf(x.w, w3.z, acc[r][2]);
      acc[r][3] = fmaf(x.x, w0.w, acc[r][3]);
      acc[r][3] = fmaf(x.y, w1.w, acc[r][3]);
      acc[r][3] = fmaf(x.z, w2.w, acc[r][3]);
      acc[r][3] = fmaf(x.w, w3.w, acc[r][3]);
    }
  }

  float4 cv = {0.f, 0.f, 0.f, 0.f};
  if (mat == 2) cv = *(const float4*)(ctv + c4);
#pragma unroll
  for (int r = 0; r < 2; ++r) {
    float4 v = {acc[r][0] + cv.x, acc[r][1] + cv.y,
                acc[r][2] + cv.z, acc[r][3] + cv.w};
    *(float4*)(g + (size_t)(r0 + rb + r) * 384 + mat * 128 + c4) = v;
  }
}

// Sparse adjacency over [gu|gr] + gate epilogue.
__global__ __launch_bounds__(256) void adj_gate(
    const float* __restrict__ adj, const float* __restrict__ g,
    const float* __restrict__ h, const float* __restrict__ deg,
    const float* __restrict__ cu, const float* __restrict__ cr,
    const float* __restrict__ bu, const float* __restrict__ br,
    float* __restrict__ z, float* __restrict__ rh)
{
  int wid = TID >> 6, lane = TID & 63;
  int b = blockIdx.y;
  int i = blockIdx.x * 4 + wid;

  int c = (lane < 32) ? 4 * lane : 128 + 4 * (lane - 32);
  const float* gb = g + (size_t)b * Sn * 384 + c;
  const float* arow = adj + ((size_t)b * Sn + i) * Sn;

  float4 acc = {0.f, 0.f, 0.f, 0.f};
  for (int j0 = 0; j0 < Sn; j0 += 64) {
    float av = arow[j0 + lane];
    unsigned long long mask = __ballot(av != 0.f);
    while (mask) {
      int jj = __ffsll((unsigned long long)mask) - 1;
      mask &= mask - 1;
      float w = __shfl(av, jj, 64);
      float4 x = *(const float4*)(gb + (size_t)(j0 + jj) * 384);
      acc.x = fmaf(w, x.x, acc.x);
      acc.y = fmaf(w, x.y, acc.y);
      acc.z = fmaf(w, x.z, acc.z);
      acc.w = fmaf(w, x.w, acc.w);
    }
  }

  size_t row = (size_t)b * Sn + i;
  float d = deg[row];
  int cc = (lane < 32) ? 4 * lane : 4 * (lane - 32);
  const float* cvp = (lane < 32) ? cu : cr;
  const float* bvp = (lane < 32) ? bu : br;
  float4 cv = *(const float4*)(cvp + cc);
  float4 bv = *(const float4*)(bvp + cc);
  float4 sg;
  sg.x = sigm(acc.x + d * cv.x + bv.x);
  sg.y = sigm(acc.y + d * cv.y + bv.y);
  sg.z = sigm(acc.z + d * cv.z + bv.z);
  sg.w = sigm(acc.w + d * cv.w + bv.w);
  if (lane < 32) {
    *(float4*)(z + row * 128 + cc) = sg;
  } else {
    float4 hv = *(const float4*)(h + row * 128 + cc);
    sg.x *= hv.x; sg.y *= hv.y; sg.z *= hv.z; sg.w *= hv.w;
    *(float4*)(rh + row * 128 + cc) = sg;
  }
}

// h_new = h_in + z*(tanh(rh@WtRT + g_t + bt) - h_in); optional row-local
// epilogue e_out = h_new @ WeT. Thread = 2 rows x 4 cols, float4 W loads.
__global__ __launch_bounds__(256) void gemm_hh(
    const float* __restrict__ rh, const float* __restrict__ g,
    const float* __restrict__ WtRT, const float* __restrict__ bt,
    const float* __restrict__ z, const float* __restrict__ h_in,
    float* __restrict__ h_out,
    const float* __restrict__ WeT, float* __restrict__ e_out)
{
  __shared__ float Xs[16 * 128];
  int r0 = blockIdx.x * 16;
  const float* xsrc = rh + (size_t)r0 * 128;
  for (int i = TID; i < 512; i += 256)
    ((float4*)Xs)[i] = ((const float4*)xsrc)[i];
  __syncthreads();

  int c4 = (TID & 31) * 4;
  int rb = (TID >> 5) * 2;
  float acc[2][4] = {};

#pragma unroll 4
  for (int k = 0; k < 128; k += 4) {
    const float* wk = WtRT + (size_t)k * 128 + c4;
    float4 w0 = *(const float4*)(wk);
    float4 w1 = *(const float4*)(wk + 128);
    float4 w2 = *(const float4*)(wk + 256);
    float4 w3 = *(const float4*)(wk + 384);
#pragma unroll
    for (int r = 0; r < 2; ++r) {
      float4 x = *(const float4*)&Xs[(rb + r) * 128 + k];
      acc[r][0] = fmaf(x.x, w0.x, acc[r][0]);
      acc[r][0] = fmaf(x.y, w1.x, acc[r][0]);
      acc[r][0] = fmaf(x.z, w2.x, acc[r][0]);
      acc[r][0] = fmaf(x.w, w3.x, acc[r][0]);
      acc[r][1] = fmaf(x.x, w0.y, acc[r][1]);
      acc[r][1] = fmaf(x.y, w1.y, acc[r][1]);
      acc[r][1] = fmaf(x.z, w2.y, acc[r][1]);
      acc[r][1] = fmaf(x.w, w3.y, acc[r][1]);
      acc[r][2] = fmaf(x.x, w0.z, acc[r][2]);
      acc[r][2] = fmaf(x.y, w1.z, acc[r][2]);
      acc[r][2] = fmaf(x.z, w2.z, acc[r][2]);
      acc[r][2] = fmaf(x.w, w3.z, acc[r][2]);
      acc[r][3] = fmaf(x.x, w0.w, acc[r][3]);
      acc[r][3] = fmaf(x.y, w1.w, acc[r][3]);
      acc[r][3] = fmaf(x.z, w2.w, acc[r][3]);
      acc[r][3] = fmaf(x.w, w3.w, acc[r][3]);
    }
  }

  float4 btv = *(const float4*)(bt + c4);
  float hn[2][4];
#pragma unroll
  for (int r = 0; r < 2; ++r) {
    size_t row = r0 + rb + r;
    float4 gt = *(const float4*)(g + row * 384 + 256 + c4);
    float4 hv = *(const float4*)(h_in + row * 128 + c4);
    float4 zv = *(const float4*)(z + row * 128 + c4);
    hn[r][0] = hv.x + zv.x * (tanhf(acc[r][0] + gt.x + btv.x) - hv.x);
    hn[r][1] = hv.y + zv.y * (tanhf(acc[r][1] + gt.y + btv.y) - hv.y);
    hn[r][2] = hv.z + zv.z * (tanhf(acc[r][2] + gt.z + btv.z) - hv.z);
    hn[r][3] = hv.w + zv.w * (tanhf(acc[r][3] + gt.w + btv.w) - hv.w);
    float4 o = {hn[r][0], hn[r][1], hn[r][2], hn[r][3]};
    *(float4*)(h_out + row * 128 + c4) = o;
  }

  if (WeT) {
    __syncthreads();
#pragma unroll
    for (int r = 0; r < 2; ++r) {
      float4 o = {hn[r][0], hn[r][1], hn[r][2], hn[r][3]};
      *(float4*)&Xs[(rb + r) * 128 + c4] = o;
    }
    __syncthreads();
    float acc2[2][4] = {};
#pragma unroll 4
    for (int k = 0; k < 128; k += 4) {
      const float* wk = WeT + (size_t)k * 128 + c4;
      float4 w0 = *(const float4*)(wk);
      float4 w1 = *(const float4*)(wk + 128);
      float4 w2 = *(const float4*)(wk + 256);
      float4 w3 = *(const float4*)(wk + 384);
#pragma unroll
      for (int r = 0; r < 2; ++r) {
        float4 x = *(const float4*)&Xs[(rb + r) * 128 + k];
        acc2[r][0] = fmaf(x.x, w0.x, acc2[r][0]);
        acc2[r][0] = fmaf(x.y, w1.x, acc2[r][0]);
        acc2[r][0] = fmaf(x.z, w2.x, acc2[r][0]);
        acc2[r][0] = fmaf(x.w, w3.x, acc2[r][0]);
        acc2[r][1] = fmaf(x.x, w0.y, acc2[r][1]);
        acc2[r][1] = fmaf(x.y, w1.y, acc2[r][1]);
        acc2[r][1] = fmaf(x.z, w2.y, acc2[r][1]);
        acc2[r][1] = fmaf(x.w, w3.y, acc2[r][1]);
        acc2[r][2] = fmaf(x.x, w0.z, acc2[r][2]);
        acc2[r][2] = fmaf(x.y, w1.z, acc2[r][2]);
        acc2[r][2] = fmaf(x.z, w2.z, acc2[r][2]);
        acc2[r][2] = fmaf(x.w, w3.z, acc2[r][2]);
        acc2[r][3] = fmaf(x.x, w0.w, acc2[r][3]);
        acc2[r][3] = fmaf(x.y, w1.w, acc2[r][3]);
        acc2[r][3] = fmaf(x.z, w2.w, acc2[r][3]);
        acc2[r][3] = fmaf(x.w, w3.w, acc2[r][3]);
      }
    }
#pragma unroll
    for (int r = 0; r < 2; ++r) {
      float4 v = {acc2[r][0], acc2[r][1], acc2[r][2], acc2[r][3]};
      *(float4*)(e_out + (size_t)(r0 + rb + r) * 128 + c4) = v;
    }
  }
}

// Y[M,128] = X[M,K] @ WT[K,128] (+bias). Used for qp (small).
__global__ __launch_bounds__(256) void gemm_wt(
    const float* __restrict__ X, const float* __restrict__ WT,
    const float* __restrict__ bias, float* __restrict__ Y,
    int M, int K)
{
  extern __shared__ float Xs[];
  int r0 = blockIdx.x * 16;
  const float* xsrc = X + (size_t)r0 * K;
  int tot4 = (16 * K) >> 2;
  for (int i = TID; i < tot4; i += 256)
    ((float4*)Xs)[i] = ((const float4*)xsrc)[i];
  __syncthreads();

  int c4 = (TID & 31) * 4;
  int rb = (TID >> 5) * 2;
  float acc[2][4] = {};

#pragma unroll 4
  for (int k = 0; k < K; k += 4) {
    const float* wk = WT + (size_t)k * 128 + c4;
    float4 w0 = *(const float4*)(wk);
    float4 w1 = *(const float4*)(wk + 128);
    float4 w2 = *(const float4*)(wk + 256);
    float4 w3 = *(const float4*)(wk + 384);
#pragma unroll
    for (int r = 0; r < 2; ++r) {
      float4 x = *(const float4*)&Xs[(rb + r) * K + k];
      acc[r][0] = fmaf(x.x, w0.x, acc[r][0]);
      acc[r][0] = fmaf(x.y, w1.x, acc[r][0]);
      acc[r][0] = fmaf(x.z, w2.x, acc[r][0]);
      acc[r][0] = fmaf(x.w, w3.x, acc[r][0]);
      acc[r][1] = fmaf(x.x, w0.y, acc[r][1]);
      acc[r][1] = fmaf(x.y, w1.y, acc[r][1]);
      acc[r][1] = fmaf(x.z, w2.y, acc[r][1]);
      acc[r][1] = fmaf(x.w, w3.y, acc[r][1]);
      acc[r][2] = fmaf(x.x, w0.z, acc[r][2]);
      acc[r][2] = fmaf(x.y, w1.z, acc[r][2]);
      acc[r][2] = fmaf(x.z, w2.z, acc[r][2]);
      acc[r][2] = fmaf(x.w, w3.z, acc[r][2]);
      acc[r][3] = fmaf(x.x, w0.w, acc[r][3]);
      acc[r][3] = fmaf(x.y, w1.w, acc[r][3]);
      acc[r][3] = fmaf(x.z, w2.w, acc[r][3]);
      acc[r][3] = fmaf(x.w, w3.w, acc[r][3]);
    }
  }

  float4 bv = {0.f, 0.f, 0.f, 0.f};
  if (bias) bv = *(const float4*)(bias + c4);
#pragma unroll
  for (int r = 0; r < 2; ++r) {
    float4 v = {acc[r][0] + bv.x, acc[r][1] + bv.y,
                acc[r][2] + bv.z, acc[r][3] + bv.w};
    *(float4*)(Y + (size_t)(r0 + rb + r) * 128 + c4) = v;
  }
}

// E[b,q,k] = mask ? exp(relu(Wa2 . relu(qp[b,q]+kp[b,k]+ba1) + ba2)) : 0
// v3: 32q x 32k per block (q split over blockIdx.y) -> 512 blocks.
__global__ __launch_bounds__(256) void scores_exp_v3(
    const float* __restrict__ qp, const float* __restrict__ kp,
    const float* __restrict__ ba1, const float* __restrict__ Wa2,
    const float* __restrict__ ba2, const float* __restrict__ am,
    const float* __restrict__ sm, float* __restrict__ E)
{
  constexpr int KT = 32, QT = 32;
  __shared__ float qs[QT][132];
  __shared__ float ks[KT][132];
  __shared__ float w2s[128];
  __shared__ float es[QT][33];

  int b = blockIdx.z, kt = blockIdx.x * KT, qt = blockIdx.y * QT;

  const float* qsrc = qp + ((size_t)b * S2n + qt) * Hn;
  for (int f = TID; f < QT * 32; f += 256) {
    int q = f >> 5, g = f & 31;
    float4 v  = ((const float4*)qsrc)[f];
    float4 bb = ((const float4*)ba1)[g];
    v.x += bb.x; v.y += bb.y; v.z += bb.z; v.w += bb.w;
    *(float4*)&qs[q][4 * g] = v;
  }
  const float* ksrc = kp + ((size_t)b * Sn + kt) * Hn;
  for (int f = TID; f < KT * 32; f += 256) {
    int k = f >> 5, g = f & 31;
    *(float4*)&ks[k][4 * g] = ((const float4*)ksrc)[f];
  }
  if (TID < 128) w2s[TID] = Wa2[TID];
  __syncthreads();

  const int q0 = (TID & 15) * 2;        // 16 groups x 2 q = 32
  const int k0 = (TID >> 4) * 2;        // 16 groups x 2 k = 32
  float acc[2][2] = {};

#pragma unroll 4
  for (int h = 0; h < 128; ++h) {
    float w  = w2s[h];
    float kv0 = ks[k0][h], kv1 = ks[k0 + 1][h];
    float qv0 = qs[q0][h], qv1 = qs[q0 + 1][h];
    acc[0][0] = fmaf(fmaxf(qv0 + kv0, 0.f), w, acc[0][0]);
    acc[0][1] = fmaf(fmaxf(qv0 + kv1, 0.f), w, acc[0][1]);
    acc[1][0] = fmaf(fmaxf(qv1 + kv0, 0.f), w, acc[1][0]);
    acc[1][1] = fmaf(fmaxf(qv1 + kv1, 0.f), w, acc[1][1]);
  }

  float b2 = ba2[0];
#pragma unroll
  for (int i = 0; i < 2; ++i) {
    float amq = am[b * S2n + qt + q0 + i];
#pragma unroll
    for (int j = 0; j < 2; ++j) {
      float m = amq * sm[b * Sn + kt + k0 + j];
      float s = fmaxf(acc[i][j] + b2, 0.f);
      es[q0 + i][k0 + j] = (m > 0.f) ? expf(s) : 0.f;
    }
  }
  __syncthreads();

  float* Eb = E + ((size_t)b * S2n + qt) * Sn + kt;
  for (int f = TID; f < QT * KT; f += 256) {
    int q = f >> 5, kin = f & 31;
    Eb[(size_t)q * Sn + kin] = es[q][kin];
  }
}

// sf[b,q,:] = (1/max(sum_k E,2e-15)) * sum_k E[b,q,k]*out[b,k,:]
__global__ __launch_bounds__(128) void attn_sf(
    const float* __restrict__ E, const float* __restrict__ out,
    float* __restrict__ sf)
{
  __shared__ float Es[512];
  __shared__ float red[2];
  int b = blockIdx.y, q = blockIdx.x, t = TID;
  const float* Erow = E + ((size_t)b * S2n + q) * Sn;
  for (int i = t; i < Sn; i += 128) Es[i] = Erow[i];
  __syncthreads();
  float part = Es[t] + Es[t + 128] + Es[t + 256] + Es[t + 384];
  part = wave_reduce_sum(part);
  if ((t & 63) == 0) red[t >> 6] = part;
  __syncthreads();
  float scale = 1.f / fmaxf(red[0] + red[1], 2e-15f);

  const float* ob = out + (size_t)b * Sn * Hn + t;
  float acc = 0.f;
#pragma unroll 8
  for (int k = 0; k < Sn; ++k) acc = fmaf(Es[k], ob[(size_t)k * Hn], acc);
  sf[((size_t)b * S2n + q) * Hn + t] = acc * scale;
}

// adv[b,s,l] = sum_h actions[b,s,h] * (weight[l] @ sf[b,s])_h + bias[l]
__global__ __launch_bounds__(128) void adv_kernel(
    const float* __restrict__ actions, const float* __restrict__ sf,
    const float* __restrict__ weight, const float* __restrict__ bias,
    float* __restrict__ adv)
{
  __shared__ float acts[128], sfs[128];
  __shared__ float red[2];
  int b = blockIdx.y, s = blockIdx.x, t = TID;
  size_t row = (size_t)b * S2n + s;
  acts[t] = actions[row * Hn + t];
  sfs[t]  = sf[row * Hn + t];
  __syncthreads();
  for (int l = 0; l < Ln; ++l) {
    const float* wr = weight + ((size_t)l * Hn + t) * Hn;
    float tmp = 0.f;
#pragma unroll 4
    for (int k = 0; k < Hn; k += 4) {
      float4 wv = *(const float4*)(wr + k);
      tmp = fmaf(wv.x, sfs[k],     tmp);
      tmp = fmaf(wv.y, sfs[k + 1], tmp);
      tmp = fmaf(wv.z, sfs[k + 2], tmp);
      tmp = fmaf(wv.w, sfs[k + 3], tmp);
    }
    float pa  = acts[t] * tmp;
    float tot = block_reduce_sum(pa, red);
    if (t == 0) adv[row * Ln + l] = tot + bias[l];
  }
}

// Fused: sem = mean_q sf ; val = Wv.sem+bv ; q = val + adv - mean(adv)
__global__ __launch_bounds__(256) void final2_kernel(
    const float* __restrict__ sf, const float* __restrict__ am,
    const float* __restrict__ Wv, const float* __restrict__ bv,
    const float* __restrict__ adv, float* __restrict__ outq)
{
  __shared__ float red[4];
  int b = blockIdx.x, t = TID;
  float num = 0.f;
  for (int i = 0; i < S2n; ++i) num += am[b * S2n + i];
  float pv = 0.f;
  if (t < Hn) {
    float s = 0.f;
    const float* sb = sf + (size_t)b * S2n * Hn + t;
    for (int q = 0; q < S2n; ++q) s += sb[(size_t)q * Hn];
    pv = Wv[t] * (s / num);
  }
  float val = block_reduce_sum(pv, red) + bv[0];
  const float* advb = adv + (size_t)b * S2n * Ln;
  float pa   = (t < S2n * Ln) ? advb[t] : 0.f;
  float mean = block_reduce_sum(pa, red) / (float)(S2n * Ln);
  for (int i = t; i < S2n * Ln; i += 256)
    outq[(size_t)b * S2n * Ln + i] = val + advb[i] - mean;
}

extern "C" void kernel_launch(void* const* d_in, const int* in_sizes, int n_in,
                              void* d_out, int out_size, void* d_ws, size_t ws_size,
                              hipStream_t stream)
{
  const float* states       = (const float*)d_in[0];
  const float* state_mask   = (const float*)d_in[1];
  const float* actions      = (const float*)d_in[2];
  const float* actions_mask = (const float*)d_in[3];
  const float* adj          = (const float*)d_in[4];
  const float* Wn  = (const float*)d_in[5];
  const float* bn  = (const float*)d_in[6];
  const float* Wu  = (const float*)d_in[7];
  const float* bu  = (const float*)d_in[8];
  const float* Wr  = (const float*)d_in[9];
  const float* br  = (const float*)d_in[10];
  const float* Wt  = (const float*)d_in[11];
  const float* bt  = (const float*)d_in[12];
  const float* Wa1 = (const float*)d_in[13];
  const float* ba1 = (const float*)d_in[14];
  const float* Wa2 = (const float*)d_in[15];
  const float* ba2 = (const float*)d_in[16];
  const float* Wv  = (const float*)d_in[17];
  const float* bvp = (const float*)d_in[18];
  const float* weight = (const float*)d_in[19];
  const float* bias   = (const float*)d_in[20];

  // Workspace layout (floats).
  float* ws   = (float*)d_ws;
  float* h    = ws;                   // [8192][128]
  float* g    = ws + (1 << 20);       // [8192][384]
  float* zp   = ws + 4 * (1 << 20);   // [8192][128]
  float* rh   = ws + 5 * (1 << 20);   // [8192][128]
  float* kp   = ws + 6 * (1 << 20);   // [8192][128]
  float* qp   = ws + 7 * (1 << 20);   // [1024][128]
  float* E    = ws + 8 * (1 << 20);   // [16][64][512]
  float* sfb  = ws + 9 * (1 << 20);   // [16][64][128]
  float* adv  = sfb + 262144;         // [16][64][3]
  float* deg  = ws + 10 * (1 << 20);  // [8192]
  float* WtRT = deg + 16384;          // [128][128]
  float* Wa1T = WtRT + 16384;         // [256][128]
  float* GuT  = Wa1T + 32768;         // [128][128]
  float* GrT  = GuT + 16384;          // [128][128]
  float* GtT  = GrT + 16384;          // [128][128]
  float* cu   = GtT + 16384;          // [128]
  float* cr   = cu + 128;             // [128]
  float* ct   = cr + 128;             // [128]

  const int M = Bn * Sn;              // 8192
  const int lds128 = 16 * 128 * 4;

  transpose2<<<dim3(8, 4, 2), 256, 0, stream>>>(Wt, Wa1, WtRT, Wa1T);
  combine_weights<<<dim3(128, 3), 128, 0, stream>>>(Wn, Wu, Wr, Wt, bn,
                                                    GuT, GrT, GtT, cu, cr, ct);
  deg_kernel<<<M / 4, 256, 0, stream>>>(adj, deg);

  for (int step = 0; step < 3; ++step) {
    const float* hin = (step == 0) ? states : h;
    gemm_g2<<<dim3(M / 16, 3), 256, 0, stream>>>(hin, GuT, GrT, GtT, ct, g);
    adj_gate<<<dim3(Sn / 4, Bn), 256, 0, stream>>>(adj, g, hin, deg,
                                                   cu, cr, bu, br, zp, rh);
    gemm_hh<<<M / 16, 256, 0, stream>>>(rh, g, WtRT, bt, zp, hin, h,
                                        step == 2 ? Wa1T + 128 * 128 : nullptr,
                                        kp);
  }

  // qp = actions @ Wa1TL
  gemm_wt<<<(Bn * S2n) / 16, 256, lds128, stream>>>(actions, Wa1T, nullptr, qp,
                                                    Bn * S2n, 128);

  scores_exp_v3<<<dim3(Sn / 32, 2, Bn), 256, 0, stream>>>(
      qp, kp, ba1, Wa2, ba2, actions_mask, state_mask, E);
  attn_sf<<<dim3(S2n, Bn), 128, 0, stream>>>(E, h, sfb);
  adv_kernel<<<dim3(S2n, Bn), 128, 0, stream>>>(actions, sfb, weight, bias, adv);
  final2_kernel<<<Bn, 256, 0, stream>>>(sfb, actions_mask, Wv, bvp, adv,
                                        (float*)d_out);
}

// Round 12
// 250.470 us; speedup vs baseline: 1.1670x; 1.1670x over previous
//
#include <hip/hip_runtime.h>
#include <math.h>

// Shapes (fixed by the reference)
constexpr int Bn  = 16;
constexpr int Sn  = 512;
constexpr int S2n = 64;
constexpr int Hn  = 128;
constexpr int Ln  = 3;

#define TID ((int)threadIdx.x)

typedef __attribute__((ext_vector_type(8))) short bf16x8;
typedef __attribute__((ext_vector_type(4))) float f32x4;

__device__ inline float wave_reduce_sum(float v) {
#pragma unroll
  for (int off = 32; off > 0; off >>= 1) v += __shfl_xor(v, off, 64);
  return v;
}

__device__ inline float block_reduce_sum(float v, float* red) {
  v = wave_reduce_sum(v);
  int w  = TID >> 6;
  int nw = (int)blockDim.x >> 6;
  if ((TID & 63) == 0) red[w] = v;
  __syncthreads();
  float s = 0.f;
  for (int i = 0; i < nw; ++i) s += red[i];
  __syncthreads();
  return s;
}

__device__ inline float sigm(float x) { return 1.f / (1.f + expf(-x)); }

// RNE float -> bf16 bits
__device__ inline unsigned short f2bf(float f) {
  unsigned int u = __float_as_uint(f);
  u = (u + 0x7fffu + ((u >> 16) & 1u)) >> 16;
  return (unsigned short)u;
}

// Transposes: z=0: WtRT[k][n] = Wt[n][128+k] (K=128); z=1: Wa1T (K=256).
__global__ __launch_bounds__(256) void transpose2(
    const float* __restrict__ Wt, const float* __restrict__ Wa1,
    float* __restrict__ WtRT, float* __restrict__ Wa1T)
{
  const float* src; float* dst; int K, woff;
  if (blockIdx.z == 0) { src = Wt;  dst = WtRT; K = 128; woff = 128; }
  else                 { src = Wa1; dst = Wa1T; K = 256; woff = 0; }
  int k0 = blockIdx.x * 32;
  if (k0 >= K) return;
  int n0 = blockIdx.y * 32;
  __shared__ float t[32][33];
  int tx = TID & 31, ty = TID >> 5;
#pragma unroll
  for (int i = 0; i < 32; i += 8)
    t[ty + i][tx] = src[(size_t)(n0 + ty + i) * 256 + woff + k0 + tx];
  __syncthreads();
#pragma unroll
  for (int i = 0; i < 32; i += 8)
    dst[(size_t)(k0 + ty + i) * 128 + n0 + tx] = t[tx][ty + i];
}

// Combined matrices: GT[k][n] = sum_c Wn[c][k]*W[n][c] (+ W[n][128+k] for u,r)
// cvec[n] = sum_c bn[c]*W[n][c].
__global__ __launch_bounds__(128) void combine_weights(
    const float* __restrict__ Wn, const float* __restrict__ Wu,
    const float* __restrict__ Wr, const float* __restrict__ Wt,
    const float* __restrict__ bn,
    float* __restrict__ GuT, float* __restrict__ GrT, float* __restrict__ GtT,
    float* __restrict__ cu, float* __restrict__ cr, float* __restrict__ ct)
{
  int n = blockIdx.x, mat = blockIdx.y;
  const float* W; float* GT; float* cv;
  if (mat == 0)      { W = Wu; GT = GuT; cv = cu; }
  else if (mat == 1) { W = Wr; GT = GrT; cv = cr; }
  else               { W = Wt; GT = GtT; cv = ct; }
  __shared__ float Ws[128], bns[128];
  __shared__ float red[2];
  int k = TID;
  Ws[k]  = W[(size_t)n * 256 + k];
  bns[k] = bn[k];
  __syncthreads();
  float acc = 0.f;
#pragma unroll 4
  for (int c = 0; c < 128; ++c)
    acc = fmaf(Wn[(size_t)c * 128 + k], Ws[c], acc);
  if (mat < 2) acc += W[(size_t)n * 256 + 128 + k];
  GT[(size_t)k * 128 + n] = acc;
  float pv = bns[k] * Ws[k];
  pv = wave_reduce_sum(pv);
  if ((k & 63) == 0) red[k >> 6] = pv;
  __syncthreads();
  if (k == 0) cv[n] = red[0] + red[1];
}

// Pack GuT/GrT/GtT into MFMA B-fragment bf16 layout.
// Bp[((mat*8+nt)*4+kc)*512 + l*8 + j] = bf16(GT[(kc*32+(l>>4)*8+j)*128 + nt*16+(l&15)])
__global__ __launch_bounds__(64) void pack_b3(
    const float* __restrict__ GuT, const float* __restrict__ GrT,
    const float* __restrict__ GtT, short* __restrict__ Bp)
{
  int kc = blockIdx.x, nt = blockIdx.y, mat = blockIdx.z;
  int l = TID;
  const float* GT = (mat == 0) ? GuT : (mat == 1) ? GrT : GtT;
  short v[8];
#pragma unroll
  for (int j = 0; j < 8; ++j)
    v[j] = (short)f2bf(GT[(size_t)(kc * 32 + (l >> 4) * 8 + j) * 128 +
                          nt * 16 + (l & 15)]);
  short* dst = Bp + (size_t)(((mat * 8 + nt) * 4 + kc) * 64 + l) * 8;
#pragma unroll
  for (int j = 0; j < 8; ++j) dst[j] = v[j];
}

// fp32 -> bf16 convert (float4 -> ushort4)
__global__ __launch_bounds__(256) void tobf16(
    const float* __restrict__ src, unsigned short* __restrict__ dst, int n4)
{
  int i = blockIdx.x * 256 + TID;
  if (i >= n4) return;
  float4 v = ((const float4*)src)[i];
  ushort4 o = {f2bf(v.x), f2bf(v.y), f2bf(v.z), f2bf(v.w)};
  ((ushort4*)dst)[i] = o;
}

// deg[row] = sum_j adj[row][j]
__global__ __launch_bounds__(256) void deg_kernel(
    const float* __restrict__ adj, float* __restrict__ deg)
{
  int wid = TID >> 6, lane = TID & 63;
  int row = blockIdx.x * 4 + wid;
  const float* ar = adj + (size_t)row * Sn;
  float4 a = ((const float4*)ar)[lane];
  float4 b = ((const float4*)ar)[64 + lane];
  float s = a.x + a.y + a.z + a.w + b.x + b.y + b.z + b.w;
  s = wave_reduce_sum(s);
  if (lane == 0) deg[row] = s;
}

// MFMA bf16 version of gemm_g: g[row][mat*128+n] = h @ G_mat (+ct for mat 2).
// Block = 4 waves x 16 rows = 64 rows; grid (M/64, 3).
__global__ __launch_bounds__(256) void gemm_g_mfma(
    const unsigned short* __restrict__ hb, const short* __restrict__ Bp,
    const float* __restrict__ ctv, float* __restrict__ g)
{
  int w = TID >> 6, l = TID & 63;
  int r0 = blockIdx.x * 64 + w * 16;
  int mat = blockIdx.y;

  // A fragments: lane l holds A[l&15][(l>>4)*8 + j], K chunks of 32.
  const unsigned short* abase = hb + (size_t)(r0 + (l & 15)) * 128 + (l >> 4) * 8;
  bf16x8 a[4];
#pragma unroll
  for (int kc = 0; kc < 4; ++kc)
    a[kc] = *(const bf16x8*)(abase + kc * 32);

  f32x4 acc[8];
#pragma unroll
  for (int nt = 0; nt < 8; ++nt) acc[nt] = (f32x4){0.f, 0.f, 0.f, 0.f};

  const short* bbase = Bp + (size_t)(mat * 8) * 4 * 512 + l * 8;
#pragma unroll
  for (int nt = 0; nt < 8; ++nt) {
#pragma unroll
    for (int kc = 0; kc < 4; ++kc) {
      bf16x8 b = *(const bf16x8*)(bbase + (nt * 4 + kc) * 512);
      acc[nt] = __builtin_amdgcn_mfma_f32_16x16x32_bf16(a[kc], b, acc[nt], 0, 0, 0);
    }
  }

  // D[row=(l>>4)*4+r][col=l&15] -> g[(r0+row)*384 + mat*128 + nt*16 + col]
  int col0 = l & 15, rb2 = (l >> 4) * 4;
  float* gout = g + (size_t)(r0 + rb2) * 384 + mat * 128 + col0;
#pragma unroll
  for (int nt = 0; nt < 8; ++nt) {
    float cadd = (mat == 2) ? ctv[nt * 16 + col0] : 0.f;
#pragma unroll
    for (int r = 0; r < 4; ++r)
      gout[(size_t)r * 384 + nt * 16] = acc[nt][r] + cadd;
  }
}

// Sparse adjacency over [gu|gr] + gate epilogue.
__global__ __launch_bounds__(256) void adj_gate(
    const float* __restrict__ adj, const float* __restrict__ g,
    const float* __restrict__ h, const float* __restrict__ deg,
    const float* __restrict__ cu, const float* __restrict__ cr,
    const float* __restrict__ bu, const float* __restrict__ br,
    float* __restrict__ z, float* __restrict__ rh)
{
  int wid = TID >> 6, lane = TID & 63;
  int b = blockIdx.y;
  int i = blockIdx.x * 4 + wid;

  int c = (lane < 32) ? 4 * lane : 128 + 4 * (lane - 32);
  const float* gb = g + (size_t)b * Sn * 384 + c;
  const float* arow = adj + ((size_t)b * Sn + i) * Sn;

  float4 acc = {0.f, 0.f, 0.f, 0.f};
  for (int j0 = 0; j0 < Sn; j0 += 64) {
    float av = arow[j0 + lane];
    unsigned long long mask = __ballot(av != 0.f);
    while (mask) {
      int jj = __ffsll((unsigned long long)mask) - 1;
      mask &= mask - 1;
      float w = __shfl(av, jj, 64);
      float4 x = *(const float4*)(gb + (size_t)(j0 + jj) * 384);
      acc.x = fmaf(w, x.x, acc.x);
      acc.y = fmaf(w, x.y, acc.y);
      acc.z = fmaf(w, x.z, acc.z);
      acc.w = fmaf(w, x.w, acc.w);
    }
  }

  size_t row = (size_t)b * Sn + i;
  float d = deg[row];
  int cc = (lane < 32) ? 4 * lane : 4 * (lane - 32);
  const float* cvp = (lane < 32) ? cu : cr;
  const float* bvp = (lane < 32) ? bu : br;
  float4 cv = *(const float4*)(cvp + cc);
  float4 bv = *(const float4*)(bvp + cc);
  float4 sg;
  sg.x = sigm(acc.x + d * cv.x + bv.x);
  sg.y = sigm(acc.y + d * cv.y + bv.y);
  sg.z = sigm(acc.z + d * cv.z + bv.z);
  sg.w = sigm(acc.w + d * cv.w + bv.w);
  if (lane < 32) {
    *(float4*)(z + row * 128 + cc) = sg;
  } else {
    float4 hv = *(const float4*)(h + row * 128 + cc);
    sg.x *= hv.x; sg.y *= hv.y; sg.z *= hv.z; sg.w *= hv.w;
    *(float4*)(rh + row * 128 + cc) = sg;
  }
}

// h_new = h_in + z*(tanh(rh@WtRT + g_t + bt) - h_in); optional row-local
// epilogue e_out = h_new @ WeT. Thread = 2 rows x 4 cols, float4 W loads.
__global__ __launch_bounds__(256) void gemm_hh(
    const float* __restrict__ rh, const float* __restrict__ g,
    const float* __restrict__ WtRT, const float* __restrict__ bt,
    const float* __restrict__ z, const float* __restrict__ h_in,
    float* __restrict__ h_out,
    const float* __restrict__ WeT, float* __restrict__ e_out)
{
  __shared__ float Xs[16 * 128];
  int r0 = blockIdx.x * 16;
  const float* xsrc = rh + (size_t)r0 * 128;
  for (int i = TID; i < 512; i += 256)
    ((float4*)Xs)[i] = ((const float4*)xsrc)[i];
  __syncthreads();

  int c4 = (TID & 31) * 4;
  int rb = (TID >> 5) * 2;
  float acc[2][4] = {};

#pragma unroll 4
  for (int k = 0; k < 128; k += 4) {
    const float* wk = WtRT + (size_t)k * 128 + c4;
    float4 w0 = *(const float4*)(wk);
    float4 w1 = *(const float4*)(wk + 128);
    float4 w2 = *(const float4*)(wk + 256);
    float4 w3 = *(const float4*)(wk + 384);
#pragma unroll
    for (int r = 0; r < 2; ++r) {
      float4 x = *(const float4*)&Xs[(rb + r) * 128 + k];
      acc[r][0] = fmaf(x.x, w0.x, acc[r][0]);
      acc[r][0] = fmaf(x.y, w1.x, acc[r][0]);
      acc[r][0] = fmaf(x.z, w2.x, acc[r][0]);
      acc[r][0] = fmaf(x.w, w3.x, acc[r][0]);
      acc[r][1] = fmaf(x.x, w0.y, acc[r][1]);
      acc[r][1] = fmaf(x.y, w1.y, acc[r][1]);
      acc[r][1] = fmaf(x.z, w2.y, acc[r][1]);
      acc[r][1] = fmaf(x.w, w3.y, acc[r][1]);
      acc[r][2] = fmaf(x.x, w0.z, acc[r][2]);
      acc[r][2] = fmaf(x.y, w1.z, acc[r][2]);
      acc[r][2] = fmaf(x.z, w2.z, acc[r][2]);
      acc[r][2] = fmaf(x.w, w3.z, acc[r][2]);
      acc[r][3] = fmaf(x.x, w0.w, acc[r][3]);
      acc[r][3] = fmaf(x.y, w1.w, acc[r][3]);
      acc[r][3] = fmaf(x.z, w2.w, acc[r][3]);
      acc[r][3] = fmaf(x.w, w3.w, acc[r][3]);
    }
  }

  float4 btv = *(const float4*)(bt + c4);
  float hn[2][4];
#pragma unroll
  for (int r = 0; r < 2; ++r) {
    size_t row = r0 + rb + r;
    float4 gt = *(const float4*)(g + row * 384 + 256 + c4);
    float4 hv = *(const float4*)(h_in + row * 128 + c4);
    float4 zv = *(const float4*)(z + row * 128 + c4);
    hn[r][0] = hv.x + zv.x * (tanhf(acc[r][0] + gt.x + btv.x) - hv.x);
    hn[r][1] = hv.y + zv.y * (tanhf(acc[r][1] + gt.y + btv.y) - hv.y);
    hn[r][2] = hv.z + zv.z * (tanhf(acc[r][2] + gt.z + btv.z) - hv.z);
    hn[r][3] = hv.w + zv.w * (tanhf(acc[r][3] + gt.w + btv.w) - hv.w);
    float4 o = {hn[r][0], hn[r][1], hn[r][2], hn[r][3]};
    *(float4*)(h_out + row * 128 + c4) = o;
  }

  if (WeT) {
    __syncthreads();
#pragma unroll
    for (int r = 0; r < 2; ++r) {
      float4 o = {hn[r][0], hn[r][1], hn[r][2], hn[r][3]};
      *(float4*)&Xs[(rb + r) * 128 + c4] = o;
    }
    __syncthreads();
    float acc2[2][4] = {};
#pragma unroll 4
    for (int k = 0; k < 128; k += 4) {
      const float* wk = WeT + (size_t)k * 128 + c4;
      float4 w0 = *(const float4*)(wk);
      float4 w1 = *(const float4*)(wk + 128);
      float4 w2 = *(const float4*)(wk + 256);
      float4 w3 = *(const float4*)(wk + 384);
#pragma unroll
      for (int r = 0; r < 2; ++r) {
        float4 x = *(const float4*)&Xs[(rb + r) * 128 + k];
        acc2[r][0] = fmaf(x.x, w0.x, acc2[r][0]);
        acc2[r][0] = fmaf(x.y, w1.x, acc2[r][0]);
        acc2[r][0] = fmaf(x.z, w2.x, acc2[r][0]);
        acc2[r][0] = fmaf(x.w, w3.x, acc2[r][0]);
        acc2[r][1] = fmaf(x.x, w0.y, acc2[r][1]);
        acc2[r][1] = fmaf(x.y, w1.y, acc2[r][1]);
        acc2[r][1] = fmaf(x.z, w2.y, acc2[r][1]);
        acc2[r][1] = fmaf(x.w, w3.y, acc2[r][1]);
        acc2[r][2] = fmaf(x.x, w0.z, acc2[r][2]);
        acc2[r][2] = fmaf(x.y, w1.z, acc2[r][2]);
        acc2[r][2] = fmaf(x.z, w2.z, acc2[r][2]);
        acc2[r][2] = fmaf(x.w, w3.z, acc2[r][2]);
        acc2[r][3] = fmaf(x.x, w0.w, acc2[r][3]);
        acc2[r][3] = fmaf(x.y, w1.w, acc2[r][3]);
        acc2[r][3] = fmaf(x.z, w2.w, acc2[r][3]);
        acc2[r][3] = fmaf(x.w, w3.w, acc2[r][3]);
      }
    }
#pragma unroll
    for (int r = 0; r < 2; ++r) {
      float4 v = {acc2[r][0], acc2[r][1], acc2[r][2], acc2[r][3]};
      *(float4*)(e_out + (size_t)(r0 + rb + r) * 128 + c4) = v;
    }
  }
}

// Y[M,128] = X[M,K] @ WT[K,128] (+bias). Used for qp (small).
__global__ __launch_bounds__(256) void gemm_wt(
    const float* __restrict__ X, const float* __restrict__ WT,
    const float* __restrict__ bias, float* __restrict__ Y,
    int M, int K)
{
  extern __shared__ float Xs[];
  int r0 = blockIdx.x * 16;
  const float* xsrc = X + (size_t)r0 * K;
  int tot4 = (16 * K) >> 2;
  for (int i = TID; i < tot4; i += 256)
    ((float4*)Xs)[i] = ((const float4*)xsrc)[i];
  __syncthreads();

  int c4 = (TID & 31) * 4;
  int rb = (TID >> 5) * 2;
  float acc[2][4] = {};

#pragma unroll 4
  for (int k = 0; k < K; k += 4) {
    const float* wk = WT + (size_t)k * 128 + c4;
    float4 w0 = *(const float4*)(wk);
    float4 w1 = *(const float4*)(wk + 128);
    float4 w2 = *(const float4*)(wk + 256);
    float4 w3 = *(const float4*)(wk + 384);
#pragma unroll
    for (int r = 0; r < 2; ++r) {
      float4 x = *(const float4*)&Xs[(rb + r) * K + k];
      acc[r][0] = fmaf(x.x, w0.x, acc[r][0]);
      acc[r][0] = fmaf(x.y, w1.x, acc[r][0]);
      acc[r][0] = fmaf(x.z, w2.x, acc[r][0]);
      acc[r][0] = fmaf(x.w, w3.x, acc[r][0]);
      acc[r][1] = fmaf(x.x, w0.y, acc[r][1]);
      acc[r][1] = fmaf(x.y, w1.y, acc[r][1]);
      acc[r][1] = fmaf(x.z, w2.y, acc[r][1]);
      acc[r][1] = fmaf(x.w, w3.y, acc[r][1]);
      acc[r][2] = fmaf(x.x, w0.z, acc[r][2]);
      acc[r][2] = fmaf(x.y, w1.z, acc[r][2]);
      acc[r][2] = fmaf(x.z, w2.z, acc[r][2]);
      acc[r][2] = fmaf(x.w, w3.z, acc[r][2]);
      acc[r][3] = fmaf(x.x, w0.w, acc[r][3]);
      acc[r][3] = fmaf(x.y, w1.w, acc[r][3]);
      acc[r][3] = fmaf(x.z, w2.w, acc[r][3]);
      acc[r][3] = fmaf(x.w, w3.w, acc[r][3]);
    }
  }

  float4 bv = {0.f, 0.f, 0.f, 0.f};
  if (bias) bv = *(const float4*)(bias + c4);
#pragma unroll
  for (int r = 0; r < 2; ++r) {
    float4 v = {acc[r][0] + bv.x, acc[r][1] + bv.y,
                acc[r][2] + bv.z, acc[r][3] + bv.w};
    *(float4*)(Y + (size_t)(r0 + rb + r) * 128 + c4) = v;
  }
}

// E[b,q,k] = mask ? exp(relu(Wa2 . relu(qp[b,q]+kp[b,k]+ba1) + ba2)) : 0
__global__ __launch_bounds__(256) void scores_exp_v3(
    const float* __restrict__ qp, const float* __restrict__ kp,
    const float* __restrict__ ba1, const float* __restrict__ Wa2,
    const float* __restrict__ ba2, const float* __restrict__ am,
    const float* __restrict__ sm, float* __restrict__ E)
{
  constexpr int KT = 32, QT = 32;
  __shared__ float qs[QT][132];
  __shared__ float ks[KT][132];
  __shared__ float w2s[128];
  __shared__ float es[QT][33];

  int b = blockIdx.z, kt = blockIdx.x * KT, qt = blockIdx.y * QT;

  const float* qsrc = qp + ((size_t)b * S2n + qt) * Hn;
  for (int f = TID; f < QT * 32; f += 256) {
    int q = f >> 5, g = f & 31;
    float4 v  = ((const float4*)qsrc)[f];
    float4 bb = ((const float4*)ba1)[g];
    v.x += bb.x; v.y += bb.y; v.z += bb.z; v.w += bb.w;
    *(float4*)&qs[q][4 * g] = v;
  }
  const float* ksrc = kp + ((size_t)b * Sn + kt) * Hn;
  for (int f = TID; f < KT * 32; f += 256) {
    int k = f >> 5, g = f & 31;
    *(float4*)&ks[k][4 * g] = ((const float4*)ksrc)[f];
  }
  if (TID < 128) w2s[TID] = Wa2[TID];
  __syncthreads();

  const int q0 = (TID & 15) * 2;
  const int k0 = (TID >> 4) * 2;
  float acc[2][2] = {};

#pragma unroll 4
  for (int h = 0; h < 128; ++h) {
    float w  = w2s[h];
    float kv0 = ks[k0][h], kv1 = ks[k0 + 1][h];
    float qv0 = qs[q0][h], qv1 = qs[q0 + 1][h];
    acc[0][0] = fmaf(fmaxf(qv0 + kv0, 0.f), w, acc[0][0]);
    acc[0][1] = fmaf(fmaxf(qv0 + kv1, 0.f), w, acc[0][1]);
    acc[1][0] = fmaf(fmaxf(qv1 + kv0, 0.f), w, acc[1][0]);
    acc[1][1] = fmaf(fmaxf(qv1 + kv1, 0.f), w, acc[1][1]);
  }

  float b2 = ba2[0];
#pragma unroll
  for (int i = 0; i < 2; ++i) {
    float amq = am[b * S2n + qt + q0 + i];
#pragma unroll
    for (int j = 0; j < 2; ++j) {
      float m = amq * sm[b * Sn + kt + k0 + j];
      float s = fmaxf(acc[i][j] + b2, 0.f);
      es[q0 + i][k0 + j] = (m > 0.f) ? expf(s) : 0.f;
    }
  }
  __syncthreads();

  float* Eb = E + ((size_t)b * S2n + qt) * Sn + kt;
  for (int f = TID; f < QT * KT; f += 256) {
    int q = f >> 5, kin = f & 31;
    Eb[(size_t)q * Sn + kin] = es[q][kin];
  }
}

// sf[b,q,:] = (1/max(sum_k E,2e-15)) * sum_k E[b,q,k]*out[b,k,:]
__global__ __launch_bounds__(128) void attn_sf(
    const float* __restrict__ E, const float* __restrict__ out,
    float* __restrict__ sf)
{
  __shared__ float Es[512];
  __shared__ float red[2];
  int b = blockIdx.y, q = blockIdx.x, t = TID;
  const float* Erow = E + ((size_t)b * S2n + q) * Sn;
  for (int i = t; i < Sn; i += 128) Es[i] = Erow[i];
  __syncthreads();
  float part = Es[t] + Es[t + 128] + Es[t + 256] + Es[t + 384];
  part = wave_reduce_sum(part);
  if ((t & 63) == 0) red[t >> 6] = part;
  __syncthreads();
  float scale = 1.f / fmaxf(red[0] + red[1], 2e-15f);

  const float* ob = out + (size_t)b * Sn * Hn + t;
  float acc = 0.f;
#pragma unroll 8
  for (int k = 0; k < Sn; ++k) acc = fmaf(Es[k], ob[(size_t)k * Hn], acc);
  sf[((size_t)b * S2n + q) * Hn + t] = acc * scale;
}

// adv[b,s,l] = sum_h actions[b,s,h] * (weight[l] @ sf[b,s])_h + bias[l]
__global__ __launch_bounds__(128) void adv_kernel(
    const float* __restrict__ actions, const float* __restrict__ sf,
    const float* __restrict__ weight, const float* __restrict__ bias,
    float* __restrict__ adv)
{
  __shared__ float acts[128], sfs[128];
  __shared__ float red[2];
  int b = blockIdx.y, s = blockIdx.x, t = TID;
  size_t row = (size_t)b * S2n + s;
  acts[t] = actions[row * Hn + t];
  sfs[t]  = sf[row * Hn + t];
  __syncthreads();
  for (int l = 0; l < Ln; ++l) {
    const float* wr = weight + ((size_t)l * Hn + t) * Hn;
    float tmp = 0.f;
#pragma unroll 4
    for (int k = 0; k < Hn; k += 4) {
      float4 wv = *(const float4*)(wr + k);
      tmp = fmaf(wv.x, sfs[k],     tmp);
      tmp = fmaf(wv.y, sfs[k + 1], tmp);
      tmp = fmaf(wv.z, sfs[k + 2], tmp);
      tmp = fmaf(wv.w, sfs[k + 3], tmp);
    }
    float pa  = acts[t] * tmp;
    float tot = block_reduce_sum(pa, red);
    if (t == 0) adv[row * Ln + l] = tot + bias[l];
  }
}

// Fused: sem = mean_q sf ; val = Wv.sem+bv ; q = val + adv - mean(adv)
__global__ __launch_bounds__(256) void final2_kernel(
    const float* __restrict__ sf, const float* __restrict__ am,
    const float* __restrict__ Wv, const float* __restrict__ bv,
    const float* __restrict__ adv, float* __restrict__ outq)
{
  __shared__ float red[4];
  int b = blockIdx.x, t = TID;
  float num = 0.f;
  for (int i = 0; i < S2n; ++i) num += am[b * S2n + i];
  float pv = 0.f;
  if (t < Hn) {
    float s = 0.f;
    const float* sb = sf + (size_t)b * S2n * Hn + t;
    for (int q = 0; q < S2n; ++q) s += sb[(size_t)q * Hn];
    pv = Wv[t] * (s / num);
  }
  float val = block_reduce_sum(pv, red) + bv[0];
  const float* advb = adv + (size_t)b * S2n * Ln;
  float pa   = (t < S2n * Ln) ? advb[t] : 0.f;
  float mean = block_reduce_sum(pa, red) / (float)(S2n * Ln);
  for (int i = t; i < S2n * Ln; i += 256)
    outq[(size_t)b * S2n * Ln + i] = val + advb[i] - mean;
}

extern "C" void kernel_launch(void* const* d_in, const int* in_sizes, int n_in,
                              void* d_out, int out_size, void* d_ws, size_t ws_size,
                              hipStream_t stream)
{
  const float* states       = (const float*)d_in[0];
  const float* state_mask   = (const float*)d_in[1];
  const float* actions      = (const float*)d_in[2];
  const float* actions_mask = (const float*)d_in[3];
  const float* adj          = (const float*)d_in[4];
  const float* Wn  = (const float*)d_in[5];
  const float* bn  = (const float*)d_in[6];
  const float* Wu  = (const float*)d_in[7];
  const float* bu  = (const float*)d_in[8];
  const float* Wr  = (const float*)d_in[9];
  const float* br  = (const float*)d_in[10];
  const float* Wt  = (const float*)d_in[11];
  const float* bt  = (const float*)d_in[12];
  const float* Wa1 = (const float*)d_in[13];
  const float* ba1 = (const float*)d_in[14];
  const float* Wa2 = (const float*)d_in[15];
  const float* ba2 = (const float*)d_in[16];
  const float* Wv  = (const float*)d_in[17];
  const float* bvp = (const float*)d_in[18];
  const float* weight = (const float*)d_in[19];
  const float* bias   = (const float*)d_in[20];

  // Workspace layout (floats).
  float* ws   = (float*)d_ws;
  float* h    = ws;                   // [8192][128]
  float* g    = ws + (1 << 20);       // [8192][384]
  float* zp   = ws + 4 * (1 << 20);   // [8192][128]
  float* rh   = ws + 5 * (1 << 20);   // [8192][128]
  float* kp   = ws + 6 * (1 << 20);   // [8192][128]
  float* qp   = ws + 7 * (1 << 20);   // [1024][128]
  float* E    = ws + 8 * (1 << 20);   // [16][64][512]
  float* sfb  = ws + 9 * (1 << 20);   // [16][64][128]
  float* adv  = sfb + 262144;         // [16][64][3]
  float* deg  = ws + 10 * (1 << 20);  // [8192]
  float* WtRT = deg + 16384;          // [128][128]
  float* Wa1T = WtRT + 16384;         // [256][128]
  float* GuT  = Wa1T + 32768;         // [128][128]
  float* GrT  = GuT + 16384;          // [128][128]
  float* GtT  = GrT + 16384;          // [128][128]
  float* cu   = GtT + 16384;          // [128]
  float* cr   = cu + 128;             // [128]
  float* ct   = cr + 128;             // [128]
  unsigned short* hb = (unsigned short*)(ws + 11 * (1 << 20)); // bf16 [8192][128]
  short* Bp = (short*)(ws + 12 * (1 << 20));                   // packed B frags

  const int M = Bn * Sn;              // 8192
  const int lds128 = 16 * 128 * 4;

  transpose2<<<dim3(8, 4, 2), 256, 0, stream>>>(Wt, Wa1, WtRT, Wa1T);
  combine_weights<<<dim3(128, 3), 128, 0, stream>>>(Wn, Wu, Wr, Wt, bn,
                                                    GuT, GrT, GtT, cu, cr, ct);
  pack_b3<<<dim3(4, 8, 3), 64, 0, stream>>>(GuT, GrT, GtT, Bp);
  deg_kernel<<<M / 4, 256, 0, stream>>>(adj, deg);

  for (int step = 0; step < 3; ++step) {
    const float* hin = (step == 0) ? states : h;
    tobf16<<<1024, 256, 0, stream>>>(hin, hb, (M * Hn) / 4);
    gemm_g_mfma<<<dim3(M / 64, 3), 256, 0, stream>>>(hb, Bp, ct, g);
    adj_gate<<<dim3(Sn / 4, Bn), 256, 0, stream>>>(adj, g, hin, deg,
                                                   cu, cr, bu, br, zp, rh);
    gemm_hh<<<M / 16, 256, 0, stream>>>(rh, g, WtRT, bt, zp, hin, h,
                                        step == 2 ? Wa1T + 128 * 128 : nullptr,
                                        kp);
  }

  // qp = actions @ Wa1TL
  gemm_wt<<<(Bn * S2n) / 16, 256, lds128, stream>>>(actions, Wa1T, nullptr, qp,
                                                    Bn * S2n, 128);

  scores_exp_v3<<<dim3(Sn / 32, 2, Bn), 256, 0, stream>>>(
      qp, kp, ba1, Wa2, ba2, actions_mask, state_mask, E);
  attn_sf<<<dim3(S2n, Bn), 128, 0, stream>>>(E, h, sfb);
  adv_kernel<<<dim3(S2n, Bn), 128, 0, stream>>>(actions, sfb, weight, bias, adv);
  final2_kernel<<<Bn, 256, 0, stream>>>(sfb, actions_mask, Wv, bvp, adv,
                                        (float*)d_out);
}